// Round 1
// baseline (1868.851 us; speedup 1.0000x reference)
//
#include <hip/hip_runtime.h>

#define LN_EPS 1e-5f

enum { EPI_NONE=0, EPI_BIAS_RES=1, EPI_BIAS_RELU=2, EPI_RELUSQ=3, EPI_GATE=4, EPI_BIAS=5 };

constexpr int BM=128, BN=128, BK=16, TM=8, TN=8;
// threads = (BM/TM)*(BN/TN) = 256

// C = A(MxK) * B + epilogue.  TRANSB: B is (N,K) row-major (C=A*B^T).
//                            !TRANSB: B is (K,N) row-major.
// All of M,N divisible by 128; K divisible by 16 for this problem.
template<bool TRANSB, int EPI>
__global__ __launch_bounds__(256)
void gemm_k(const float* __restrict__ A, const float* __restrict__ Bm,
            float* __restrict__ C, int M, int N, int K,
            int lda, int ldb, int ldc,
            const float* __restrict__ bias,
            const float* __restrict__ ext, int ldext,
            float scale)
{
    __shared__ float As[BK][BM+4];
    __shared__ float Bs[BK][BN+4];
    const int tid = threadIdx.x;
    const int m0 = blockIdx.y * BM;
    const int n0 = blockIdx.x * BN;
    const int tx = tid & 15;        // 16 cols of threads
    const int ty = tid >> 4;        // 16 rows of threads
    const int ar = tid >> 2;        // 0..63 : tile row for loads
    const int ac = (tid & 3) * 4;   // 0,4,8,12 : k-offset (float4)

    float acc[TM][TN];
#pragma unroll
    for (int i=0;i<TM;i++)
#pragma unroll
        for (int j=0;j<TN;j++) acc[i][j]=0.f;

    for (int k0=0;k0<K;k0+=BK) {
        // ---- stage A tile (BM x BK), store transposed As[k][m]
#pragma unroll
        for (int r=0;r<2;r++) {
            const int row = ar + r*64;
            const float4 v = *(const float4*)(A + (size_t)(m0+row)*lda + k0 + ac);
            As[ac+0][row]=v.x; As[ac+1][row]=v.y; As[ac+2][row]=v.z; As[ac+3][row]=v.w;
        }
        // ---- stage B tile as Bs[k][n]
        if (TRANSB) {
#pragma unroll
            for (int r=0;r<2;r++) {
                const int row = ar + r*64;   // n index
                const float4 v = *(const float4*)(Bm + (size_t)(n0+row)*ldb + k0 + ac);
                Bs[ac+0][row]=v.x; Bs[ac+1][row]=v.y; Bs[ac+2][row]=v.z; Bs[ac+3][row]=v.w;
            }
        } else {
#pragma unroll
            for (int r=0;r<2;r++) {
                const int f = tid + r*256;
                const int kr = f >> 5;          // 0..15
                const int nc = (f & 31) * 4;    // 0..124
                const float4 v = *(const float4*)(Bm + (size_t)(k0+kr)*ldb + n0 + nc);
                *(float4*)&Bs[kr][nc] = v;
            }
        }
        __syncthreads();
#pragma unroll
        for (int k=0;k<BK;k++) {
            float a[TM], bv[TN];
#pragma unroll
            for (int i=0;i<TM;i+=4) *(float4*)&a[i]  = *(const float4*)&As[k][ty*TM+i];
#pragma unroll
            for (int j=0;j<TN;j+=4) *(float4*)&bv[j] = *(const float4*)&Bs[k][tx*TN+j];
#pragma unroll
            for (int i=0;i<TM;i++)
#pragma unroll
                for (int j=0;j<TN;j++)
                    acc[i][j] = fmaf(a[i], bv[j], acc[i][j]);
        }
        __syncthreads();
    }

    // ---- epilogue + store (float4)
#pragma unroll
    for (int i=0;i<TM;i++) {
        const int m = m0 + ty*TM + i;
#pragma unroll
        for (int j0=0;j0<TN;j0+=4) {
            const int n = n0 + tx*TN + j0;
            float4 c = make_float4(acc[i][j0], acc[i][j0+1], acc[i][j0+2], acc[i][j0+3]);
            if (EPI==EPI_BIAS_RES || EPI==EPI_BIAS_RELU || EPI==EPI_BIAS) {
                c.x += bias[n]; c.y += bias[n+1]; c.z += bias[n+2]; c.w += bias[n+3];
            }
            if (EPI==EPI_BIAS_RES) {
                const float4 e = *(const float4*)(ext + (size_t)m*ldext + n);
                c.x+=e.x; c.y+=e.y; c.z+=e.z; c.w+=e.w;
            }
            if (EPI==EPI_GATE) {
                const float4 e = *(const float4*)(ext + (size_t)m*ldext + n);
                c.x*=e.x; c.y*=e.y; c.z*=e.z; c.w*=e.w;
            }
            if (EPI==EPI_BIAS_RELU) {
                c.x=fmaxf(c.x,0.f); c.y=fmaxf(c.y,0.f); c.z=fmaxf(c.z,0.f); c.w=fmaxf(c.w,0.f);
            }
            if (EPI==EPI_RELUSQ) {
                float t;
                t=fmaxf(c.x*scale,0.f); c.x=t*t;
                t=fmaxf(c.y*scale,0.f); c.y=t*t;
                t=fmaxf(c.z*scale,0.f); c.z=t*t;
                t=fmaxf(c.w*scale,0.f); c.w=t*t;
            }
            *(float4*)(C + (size_t)m*ldc + n) = c;
        }
    }
}

// Row LayerNorm over D=512. 256 threads, 2 elements each.
template<bool ADD_RES>
__global__ __launch_bounds__(256)
void ln_k(const float* __restrict__ in, const float* __restrict__ g,
          const float* __restrict__ b, const float* __restrict__ res,
          float* __restrict__ out)
{
    const int D_ = 512;
    const int row = blockIdx.x;
    const int tid = threadIdx.x;
    const float2 v = *(const float2*)(in + (size_t)row*D_ + tid*2);
    float s  = v.x + v.y;
    float ss = v.x*v.x + v.y*v.y;
#pragma unroll
    for (int off=32; off>0; off>>=1) {
        s  += __shfl_down(s,  off);
        ss += __shfl_down(ss, off);
    }
    __shared__ float sbuf[8], ssbuf[8];
    const int wid = tid >> 6, lane = tid & 63;
    if (lane==0){ sbuf[wid]=s; ssbuf[wid]=ss; }
    __syncthreads();
    if (tid==0) {
        float S=0.f, SS=0.f;
#pragma unroll
        for (int i=0;i<4;i++){ S+=sbuf[i]; SS+=ssbuf[i]; }
        const float mean = S * (1.f/512.f);
        const float var  = SS * (1.f/512.f) - mean*mean;
        sbuf[4]  = mean;
        ssbuf[4] = rsqrtf(var + LN_EPS);
    }
    __syncthreads();
    const float mean = sbuf[4], rstd = ssbuf[4];
    const float2 gg = *(const float2*)(g + tid*2);
    const float2 bb = *(const float2*)(b + tid*2);
    float2 o;
    o.x = (v.x-mean)*rstd*gg.x + bb.x;
    o.y = (v.y-mean)*rstd*gg.y + bb.y;
    if (ADD_RES) {
        const float2 r = *(const float2*)(res + (size_t)row*D_ + tid*2);
        o.x += r.x; o.y += r.y;
    }
    *(float2*)(out + (size_t)row*D_ + tid*2) = o;
}

extern "C" void kernel_launch(void* const* d_in, const int* in_sizes, int n_in,
                              void* d_out, int out_size, void* d_ws, size_t ws_size,
                              hipStream_t stream)
{
    const float* x  = (const float*)d_in[0];
    const float* Wm = (const float*)d_in[1];
    const float* bm = (const float*)d_in[2];
    const float* g1 = (const float*)d_in[3];
    const float* b1 = (const float*)d_in[4];
    const float* Wh = (const float*)d_in[5];
    const float* bh = (const float*)d_in[6];
    const float* Wq = (const float*)d_in[7];
    const float* bq = (const float*)d_in[8];
    const float* Wb = (const float*)d_in[9];
    const float* Wo = (const float*)d_in[10];
    const float* bo = (const float*)d_in[11];
    const float* g2 = (const float*)d_in[12];
    const float* b2 = (const float*)d_in[13];
    float* out = (float*)d_out;

    const int Bn=4, S=2048, D=512, QKD=256, HID=1536;
    const int M = Bn*S;            // 8192
    const int H2 = 2*HID;          // 3072

    // workspace layout (floats); normed region is reused as the per-batch A buffer
    // (normed is dead after the Z GEMM; A_b is 2048*2048 == 8192*512 floats)
    float* ws = (float*)d_ws;
    size_t off = 0;
    float* normed = ws + off; off += (size_t)M*D;     // 4.19M f (also A buffer)
    float* h      = ws + off; off += (size_t)M*H2;    // 25.2M f
    float* Z      = ws + off; off += (size_t)M*QKD;   // 2.1M f
    float* ZWb    = ws + off; off += (size_t)M*QKD;   // 2.1M f
    float* Vg     = ws + off; off += (size_t)M*HID;   // 12.6M f
    float* ybuf   = ws + off; off += (size_t)M*D;     // 4.19M f (y, later t)
    float* Abuf   = normed;
    (void)ws_size; (void)in_sizes; (void)n_in; (void)out_size;

    dim3 blk(256);

    // 1. y = x@Wm^T + bm + x
    gemm_k<true, EPI_BIAS_RES><<<dim3(D/BN, M/BM, 1), blk, 0, stream>>>(
        x, Wm, ybuf, M, D, D, D, D, D, bm, x, D, 1.f);
    // 2. normed = LN(y; g1,b1)
    ln_k<false><<<dim3(M), blk, 0, stream>>>(ybuf, g1, b1, nullptr, normed);
    // 3. h = relu(normed@Wh^T + bh)   (v | gate)
    gemm_k<true, EPI_BIAS_RELU><<<dim3(H2/BN, M/BM, 1), blk, 0, stream>>>(
        normed, Wh, h, M, H2, D, D, D, H2, bh, nullptr, 0, 1.f);
    // 4. Z = relu(normed@Wq^T + bq)
    gemm_k<true, EPI_BIAS_RELU><<<dim3(QKD/BN, M/BM, 1), blk, 0, stream>>>(
        normed, Wq, Z, M, QKD, D, D, D, QKD, bq, nullptr, 0, 1.f);
    // 5. ZWb = Z @ Wb            (NN)
    gemm_k<false, EPI_NONE><<<dim3(QKD/BN, M/BM, 1), blk, 0, stream>>>(
        Z, Wb, ZWb, M, QKD, QKD, QKD, QKD, QKD, nullptr, nullptr, 0, 1.f);
    // 6. per batch: A = relu(ZWb_b @ Z_b^T / S)^2 ; Vg_b = (A @ v_b) * gate_b
    for (int b=0;b<Bn;b++) {
        const float* ZWb_b = ZWb + (size_t)b*S*QKD;
        const float* Z_b   = Z   + (size_t)b*S*QKD;
        const float* h_b   = h   + (size_t)b*S*H2;
        float*       Vg_b  = Vg  + (size_t)b*S*HID;
        gemm_k<true, EPI_RELUSQ><<<dim3(S/BN, S/BM, 1), blk, 0, stream>>>(
            ZWb_b, Z_b, Abuf, S, S, QKD, QKD, QKD, S, nullptr, nullptr, 0, 1.f/(float)S);
        gemm_k<false, EPI_GATE><<<dim3(HID/BN, S/BM, 1), blk, 0, stream>>>(
            Abuf, h_b, Vg_b, S, HID, S, S, H2, HID, nullptr, h_b + HID, H2, 1.f);
    }
    // 7. t = Vg@Wo^T + bo
    gemm_k<true, EPI_BIAS><<<dim3(D/BN, M/BM, 1), blk, 0, stream>>>(
        Vg, Wo, ybuf, M, D, HID, HID, HID, D, bo, nullptr, 0, 1.f);
    // 8. out = LN(t; g2,b2) + x
    ln_k<true><<<dim3(M), blk, 0, stream>>>(ybuf, g2, b2, x, out);
}

// Round 2
// 450.143 us; speedup vs baseline: 4.1517x; 4.1517x over previous
//
#include <hip/hip_runtime.h>

typedef unsigned short u16;
typedef __attribute__((ext_vector_type(8))) short short8;
typedef __attribute__((ext_vector_type(4))) float f32x4;

#define LN_EPS 1e-5f

__device__ __forceinline__ u16 f2bf(float f){
    union { float f; unsigned u; } c; c.f = f;
    unsigned u = c.u + 0x7FFFu + ((c.u >> 16) & 1u);
    return (u16)(u >> 16);
}
__device__ __forceinline__ float bf2f(u16 h){
    union { unsigned u; float f; } c; c.u = ((unsigned)h) << 16;
    return c.f;
}

enum { EPI_NONE=0, EPI_BIAS_RES, EPI_BIAS_RELU, EPI_RELUSQ, EPI_GATE, EPI_BIAS, EPI_HSPLIT };

__device__ __forceinline__ void gl2lds16(const u16* g, void* lds){
    __builtin_amdgcn_global_load_lds(
        (const __attribute__((address_space(1))) unsigned*)g,
        (__attribute__((address_space(3))) unsigned*)lds, 16, 0, 0);
}

// C(MxN) = A(MxK) @ B^T, A row-major (lda), B row-major N x K (ldb).
// bf16 inputs, fp32 MFMA accumulation. 128x128 tile, BK=32, 4 waves.
template<int EPI, bool OUT_BF16>
__global__ __launch_bounds__(256)
void mgemm(const u16* __restrict__ A, const u16* __restrict__ B, void* __restrict__ Cv,
           int K, int lda, int ldb, int ldc,
           long sAb, long sBb, long sCb,
           const float* __restrict__ bias,
           const void* __restrict__ ext, int ldext, long sEb,
           float scale, u16* __restrict__ out2, int hsplit)
{
    __shared__ u16 sA[4096];   // [ks 0..3][m 0..127][8]  = 8 KB
    __shared__ u16 sB[4096];
    const int tid = threadIdx.x;
    const int m0 = blockIdx.y * 128, n0 = blockIdx.x * 128;
    const int z  = blockIdx.z;
    const u16* Az = A + (size_t)z * sAb;
    const u16* Bz = B + (size_t)z * sBb;

    const int lane = tid & 63, quad = lane >> 4, l15 = lane & 15;
    const int wave = tid >> 6;
    const int wm = (wave >> 1) * 64, wn = (wave & 1) * 64;

    const u16* gA[2]; const u16* gB[2]; int lo[2];
#pragma unroll
    for (int r = 0; r < 2; r++){
        const int c = tid + r * 256;            // chunk id 0..511
        gA[r] = Az + (size_t)(m0 + (c & 127)) * lda + (c >> 7) * 8;
        gB[r] = Bz + (size_t)(n0 + (c & 127)) * ldb + (c >> 7) * 8;
        lo[r] = ((tid & 192) + r * 256) * 16;   // wave-uniform LDS byte base
    }

    f32x4 acc[4][4];
#pragma unroll
    for (int i = 0; i < 4; i++)
#pragma unroll
        for (int j = 0; j < 4; j++) acc[i][j] = (f32x4){0.f,0.f,0.f,0.f};

    const u16* fA = sA + quad * 1024 + (wm + l15) * 8;
    const u16* fB = sB + quad * 1024 + (wn + l15) * 8;

    for (int k0 = 0; k0 < K; k0 += 32){
#pragma unroll
        for (int r = 0; r < 2; r++){
            gl2lds16(gA[r] + k0, (char*)sA + lo[r]);
            gl2lds16(gB[r] + k0, (char*)sB + lo[r]);
        }
        __syncthreads();
        short8 a[4], b[4];
#pragma unroll
        for (int t = 0; t < 4; t++){
            a[t] = *(const short8*)(fA + t * 128);
            b[t] = *(const short8*)(fB + t * 128);
        }
#pragma unroll
        for (int i = 0; i < 4; i++)
#pragma unroll
            for (int j = 0; j < 4; j++)
                acc[i][j] = __builtin_amdgcn_mfma_f32_16x16x32_bf16(a[i], b[j], acc[i][j], 0, 0, 0);
        __syncthreads();
    }

    float* Cf = (float*)Cv; u16* Ch = (u16*)Cv;
    const size_t zc = (size_t)z * sCb;
#pragma unroll
    for (int i = 0; i < 4; i++){
#pragma unroll
        for (int j = 0; j < 4; j++){
            const int n = n0 + wn + j * 16 + l15;
            float bs = 0.f;
            if (EPI==EPI_BIAS_RES || EPI==EPI_BIAS_RELU || EPI==EPI_BIAS || EPI==EPI_HSPLIT)
                bs = bias[n];
#pragma unroll
            for (int r = 0; r < 4; r++){
                const int m = m0 + wm + i * 16 + quad * 4 + r;
                float v = acc[i][j][r] + bs;
                if (EPI==EPI_BIAS_RES)
                    v += ((const float*)ext)[(size_t)m * ldext + n];
                if (EPI==EPI_BIAS_RELU || EPI==EPI_HSPLIT)
                    v = fmaxf(v, 0.f);
                if (EPI==EPI_RELUSQ){ float t = fmaxf(v * scale, 0.f); v = t * t; }
                if (EPI==EPI_GATE)
                    v *= bf2f(((const u16*)ext)[(size_t)z * sEb + (size_t)m * ldext + n]);
                if (EPI==EPI_HSPLIT){
                    if (n < hsplit) Ch[(size_t)m * ldc + n] = f2bf(v);
                    else            out2[(size_t)m * ldc + n - hsplit] = f2bf(v);
                } else if (OUT_BF16){
                    Ch[zc + (size_t)m * ldc + n] = f2bf(v);
                } else {
                    Cf[zc + (size_t)m * ldc + n] = v;
                }
            }
        }
    }
}

// Row LayerNorm over D=512, 256 threads x 2 elements.
template<bool OUT_BF, bool ADD_RES>
__global__ __launch_bounds__(256)
void ln_k(const float* __restrict__ in, const float* __restrict__ g,
          const float* __restrict__ b, const float* __restrict__ res,
          void* __restrict__ out)
{
    const int row = blockIdx.x, tid = threadIdx.x;
    const float2 v = *(const float2*)(in + (size_t)row * 512 + tid * 2);
    float s = v.x + v.y, ss = v.x * v.x + v.y * v.y;
#pragma unroll
    for (int off = 32; off > 0; off >>= 1){
        s  += __shfl_down(s,  off);
        ss += __shfl_down(ss, off);
    }
    __shared__ float sbuf[8], ssbuf[8];
    const int wid = tid >> 6, lane = tid & 63;
    if (lane == 0){ sbuf[wid] = s; ssbuf[wid] = ss; }
    __syncthreads();
    if (tid == 0){
        float S = 0.f, SS = 0.f;
#pragma unroll
        for (int i = 0; i < 4; i++){ S += sbuf[i]; SS += ssbuf[i]; }
        const float mean = S * (1.f/512.f);
        const float var  = SS * (1.f/512.f) - mean * mean;
        sbuf[4]  = mean;
        ssbuf[4] = rsqrtf(var + LN_EPS);
    }
    __syncthreads();
    const float mean = sbuf[4], rstd = ssbuf[4];
    const float2 gg = *(const float2*)(g + tid * 2);
    const float2 bb = *(const float2*)(b + tid * 2);
    float ox = (v.x - mean) * rstd * gg.x + bb.x;
    float oy = (v.y - mean) * rstd * gg.y + bb.y;
    if (ADD_RES){
        const float2 r = *(const float2*)(res + (size_t)row * 512 + tid * 2);
        ox += r.x; oy += r.y;
    }
    if (OUT_BF){
        unsigned pk = ((unsigned)f2bf(oy) << 16) | (unsigned)f2bf(ox);
        ((unsigned*)out)[(size_t)row * 256 + tid] = pk;
    } else {
        *(float2*)((float*)out + (size_t)row * 512 + tid * 2) = make_float2(ox, oy);
    }
}

__global__ __launch_bounds__(256)
void cast_k(const float* __restrict__ in, u16* __restrict__ out, int n4){
    int i = blockIdx.x * 256 + threadIdx.x;
    if (i < n4){
        float4 v = ((const float4*)in)[i];
        ushort4 o;
        o.x = f2bf(v.x); o.y = f2bf(v.y); o.z = f2bf(v.z); o.w = f2bf(v.w);
        ((ushort4*)out)[i] = o;
    }
}

// WbT[e][d] = bf16(Wb[d][e]), 256x256
__global__ __launch_bounds__(256)
void wbt_k(const float* __restrict__ Wb, u16* __restrict__ WbT){
    int i = blockIdx.x * 256 + threadIdx.x;
    int e = i >> 8, d = i & 255;
    WbT[e * 256 + d] = f2bf(Wb[d * 256 + e]);
}

// vT[b][h][s] = v[b][s][h], bf16, 64x64 tiles
__global__ __launch_bounds__(256)
void tr_k(const u16* __restrict__ v, u16* __restrict__ vT, int S, int HID){
    const int b = blockIdx.z;
    const int h0 = blockIdx.x * 64, s0 = blockIdx.y * 64;
    __shared__ u16 t[64][68];
    const u16* vb = v + (size_t)b * S * HID;
    u16* vTb = vT + (size_t)b * HID * S;
    const int tid = threadIdx.x;
#pragma unroll
    for (int i = 0; i < 4; i++){
        int idx = tid + i * 256;
        int r = idx >> 4, c4 = (idx & 15) * 4;
        ushort4 u = *(const ushort4*)(vb + (size_t)(s0 + r) * HID + h0 + c4);
        t[r][c4] = u.x; t[r][c4+1] = u.y; t[r][c4+2] = u.z; t[r][c4+3] = u.w;
    }
    __syncthreads();
#pragma unroll
    for (int i = 0; i < 4; i++){
        int idx = tid + i * 256;
        int r = idx >> 4, c4 = (idx & 15) * 4;
        ushort4 u;
        u.x = t[c4][r]; u.y = t[c4+1][r]; u.z = t[c4+2][r]; u.w = t[c4+3][r];
        *(ushort4*)(vTb + (size_t)(h0 + r) * S + s0 + c4) = u;
    }
}

extern "C" void kernel_launch(void* const* d_in, const int* in_sizes, int n_in,
                              void* d_out, int out_size, void* d_ws, size_t ws_size,
                              hipStream_t stream)
{
    const float* x  = (const float*)d_in[0];
    const float* Wm = (const float*)d_in[1];
    const float* bm = (const float*)d_in[2];
    const float* g1 = (const float*)d_in[3];
    const float* b1 = (const float*)d_in[4];
    const float* Wh = (const float*)d_in[5];
    const float* bh = (const float*)d_in[6];
    const float* Wq = (const float*)d_in[7];
    const float* bq = (const float*)d_in[8];
    const float* Wb = (const float*)d_in[9];
    const float* Wo = (const float*)d_in[10];
    const float* bo = (const float*)d_in[11];
    const float* g2 = (const float*)d_in[12];
    const float* b2 = (const float*)d_in[13];
    float* out = (float*)d_out;
    (void)in_sizes; (void)n_in; (void)out_size; (void)ws_size;

    const int Bn=4, S=2048, D=512, QKD=256, HID=1536, H2=3072;
    const int M = Bn * S; // 8192

    char* p = (char*)d_ws;
    auto alloc = [&](size_t bytes)->void*{ void* r = p; p += (bytes + 255) & ~(size_t)255; return r; };
    u16*  xbf  = (u16*) alloc((size_t)M*D*2);     // later reused as normed_bf
    u16*  Wmbf = (u16*) alloc((size_t)D*D*2);
    u16*  Whbf = (u16*) alloc((size_t)H2*D*2);
    u16*  Wqbf = (u16*) alloc((size_t)QKD*D*2);
    u16*  Wobf = (u16*) alloc((size_t)D*HID*2);
    u16*  WbT  = (u16*) alloc((size_t)QKD*QKD*2);
    float* ybuf= (float*)alloc((size_t)M*D*4);
    u16*  Zb   = (u16*) alloc((size_t)M*QKD*2);
    u16*  ZWbb = (u16*) alloc((size_t)M*QKD*2);
    u16*  vbf  = (u16*) alloc((size_t)M*HID*2);
    u16*  gbf  = (u16*) alloc((size_t)M*HID*2);
    u16*  vT   = (u16*) alloc((size_t)M*HID*2);
    u16*  Abuf = (u16*) alloc((size_t)M*S*2);
    u16*  Vgbf = (u16*) alloc((size_t)M*HID*2);
    u16*  nrm  = xbf;

    dim3 blk(256);

    // casts to bf16
    cast_k<<<dim3(M*D/1024),       blk, 0, stream>>>(x,  xbf,  M*D/4);
    cast_k<<<dim3(D*D/1024),       blk, 0, stream>>>(Wm, Wmbf, D*D/4);
    cast_k<<<dim3(H2*D/1024),      blk, 0, stream>>>(Wh, Whbf, H2*D/4);
    cast_k<<<dim3(QKD*D/1024),     blk, 0, stream>>>(Wq, Wqbf, QKD*D/4);
    cast_k<<<dim3(D*HID/1024),     blk, 0, stream>>>(Wo, Wobf, D*HID/4);
    wbt_k<<<dim3(QKD*QKD/256),     blk, 0, stream>>>(Wb, WbT);

    // 1. y = x@Wm^T + bm + x   (fp32 out)
    mgemm<EPI_BIAS_RES,false><<<dim3(D/128, M/128, 1), blk, 0, stream>>>(
        xbf, Wmbf, ybuf, D, D, D, D, 0,0,0, bm, x, D, 0, 1.f, nullptr, 0);
    // 2. normed = LN(y) -> bf16
    ln_k<true,false><<<dim3(M), blk, 0, stream>>>(ybuf, g1, b1, nullptr, nrm);
    // 3. h = relu(normed@Wh^T + bh) -> v_bf | gate_bf
    mgemm<EPI_HSPLIT,true><<<dim3(H2/128, M/128, 1), blk, 0, stream>>>(
        nrm, Whbf, vbf, D, D, D, HID, 0,0,0, bh, nullptr, 0, 0, 1.f, gbf, HID);
    // 4. Z = relu(normed@Wq^T + bq) -> bf16
    mgemm<EPI_BIAS_RELU,true><<<dim3(QKD/128, M/128, 1), blk, 0, stream>>>(
        nrm, Wqbf, Zb, D, D, D, QKD, 0,0,0, bq, nullptr, 0, 0, 1.f, nullptr, 0);
    // 5. ZWb = Z @ Wb -> bf16   (B = WbT, N x K)
    mgemm<EPI_NONE,true><<<dim3(QKD/128, M/128, 1), blk, 0, stream>>>(
        Zb, WbT, ZWbb, QKD, QKD, QKD, QKD, 0,0,0, nullptr, nullptr, 0, 0, 1.f, nullptr, 0);
    // 6a. A = relu(ZWb_b @ Z_b^T / S)^2 -> bf16, batched over z
    mgemm<EPI_RELUSQ,true><<<dim3(S/128, S/128, Bn), blk, 0, stream>>>(
        ZWbb, Zb, Abuf, QKD, QKD, QKD, S,
        (long)S*QKD, (long)S*QKD, (long)S*S,
        nullptr, nullptr, 0, 0, 1.f/(float)S, nullptr, 0);
    // 6b. vT = transpose(v) per batch
    tr_k<<<dim3(HID/64, S/64, Bn), blk, 0, stream>>>(vbf, vT, S, HID);
    // 6c. Vg = (A @ v) * gate -> bf16, batched
    mgemm<EPI_GATE,true><<<dim3(HID/128, S/128, Bn), blk, 0, stream>>>(
        Abuf, vT, Vgbf, S, S, S, HID,
        (long)S*S, (long)HID*S, (long)S*HID,
        nullptr, gbf, HID, (long)S*HID, 1.f, nullptr, 0);
    // 7. t = Vg@Wo^T + bo  (fp32 out)
    mgemm<EPI_BIAS,false><<<dim3(D/128, M/128, 1), blk, 0, stream>>>(
        Vgbf, Wobf, ybuf, HID, HID, HID, D, 0,0,0, bo, nullptr, 0, 0, 1.f, nullptr, 0);
    // 8. out = LN(t) + x
    ln_k<false,true><<<dim3(M), blk, 0, stream>>>(ybuf, g2, b2, x, out);
}

// Round 4
// 371.621 us; speedup vs baseline: 5.0289x; 1.2113x over previous
//
#include <hip/hip_runtime.h>

typedef unsigned short u16;
typedef unsigned char u8;
typedef __attribute__((ext_vector_type(8))) short short8;
typedef __attribute__((ext_vector_type(4))) float f32x4;

#define LN_EPS 1e-5f
// fp8 exponent-shift scales: keep A (typ ~3e-4) and v (typ ~0.4) out of the
// e4m3 subnormal floor (min normal 2^-6). Undone in mgemm8's epilogue.
#define SCALE_A 4096.f     // 2^12; clip bound A<=448/4096=0.109 -> |QK|<=0.33 (est max 0.135)
#define SCALE_V 8.f        // 2^3;  v max ~3 -> 24 << 448
#define INV_SCALE_AV (1.f/32768.f)

__device__ __forceinline__ u16 f2bf(float f){
    union { float f; unsigned u; } c; c.f = f;
    unsigned u = c.u + 0x7FFFu + ((c.u >> 16) & 1u);
    return (u16)(u >> 16);
}
__device__ __forceinline__ float bf2f(u16 h){
    union { unsigned u; float f; } c; c.u = ((unsigned)h) << 16;
    return c.f;
}
__device__ __forceinline__ u8 f2fp8(float f){
    int r = __builtin_amdgcn_cvt_pk_fp8_f32(f, 0.f, 0, false);
    return (u8)(r & 0xFF);
}

enum { EPI_NONE=0, EPI_BIAS_RES, EPI_BIAS_RELU, EPI_RELUSQ, EPI_GATE, EPI_BIAS, EPI_HSPLIT };
enum { OT_F32=0, OT_BF16=1, OT_FP8=2 };

__device__ __forceinline__ void gl2lds16(const void* g, void* lds){
    __builtin_amdgcn_global_load_lds(
        (const __attribute__((address_space(1))) unsigned*)g,
        (__attribute__((address_space(3))) unsigned*)lds, 16, 0, 0);
}

// ---------------- bf16 MFMA GEMM: C(MxN) = A(MxK) @ B^T ----------------
template<int EPI, int OT>
__global__ __launch_bounds__(256)
void mgemm(const u16* __restrict__ A, const u16* __restrict__ B, void* __restrict__ Cv,
           int K, int lda, int ldb, int ldc,
           long sAb, long sBb, long sCb,
           const float* __restrict__ bias,
           const void* __restrict__ ext, int ldext, long sEb,
           float scale, u16* __restrict__ out2, int hsplit)
{
    __shared__ u16 sA[4096];   // [ks 0..3][m 0..127][8]
    __shared__ u16 sB[4096];
    const int tid = threadIdx.x;
    const int m0 = blockIdx.y * 128, n0 = blockIdx.x * 128;
    const int z  = blockIdx.z;
    const u16* Az = A + (size_t)z * sAb;
    const u16* Bz = B + (size_t)z * sBb;

    const int lane = tid & 63, quad = lane >> 4, l15 = lane & 15;
    const int wave = tid >> 6;
    const int wm = (wave >> 1) * 64, wn = (wave & 1) * 64;

    const u16* gA[2]; const u16* gB[2]; int lo[2];
#pragma unroll
    for (int r = 0; r < 2; r++){
        const int c = tid + r * 256;
        gA[r] = Az + (size_t)(m0 + (c & 127)) * lda + (c >> 7) * 8;
        gB[r] = Bz + (size_t)(n0 + (c & 127)) * ldb + (c >> 7) * 8;
        lo[r] = ((tid & 192) + r * 256) * 16;
    }

    f32x4 acc[4][4];
#pragma unroll
    for (int i = 0; i < 4; i++)
#pragma unroll
        for (int j = 0; j < 4; j++) acc[i][j] = (f32x4){0.f,0.f,0.f,0.f};

    const u16* fA = sA + quad * 1024 + (wm + l15) * 8;
    const u16* fB = sB + quad * 1024 + (wn + l15) * 8;

    for (int k0 = 0; k0 < K; k0 += 32){
#pragma unroll
        for (int r = 0; r < 2; r++){
            gl2lds16(gA[r] + k0, (char*)sA + lo[r]);
            gl2lds16(gB[r] + k0, (char*)sB + lo[r]);
        }
        __syncthreads();
        short8 a[4], b[4];
#pragma unroll
        for (int t = 0; t < 4; t++){
            a[t] = *(const short8*)(fA + t * 128);
            b[t] = *(const short8*)(fB + t * 128);
        }
#pragma unroll
        for (int i = 0; i < 4; i++)
#pragma unroll
            for (int j = 0; j < 4; j++)
                acc[i][j] = __builtin_amdgcn_mfma_f32_16x16x32_bf16(a[i], b[j], acc[i][j], 0, 0, 0);
        __syncthreads();
    }

    float* Cf = (float*)Cv; u16* Ch = (u16*)Cv; u8* C8 = (u8*)Cv;
    const size_t zc = (size_t)z * sCb;
#pragma unroll
    for (int i = 0; i < 4; i++){
#pragma unroll
        for (int j = 0; j < 4; j++){
            const int n = n0 + wn + j * 16 + l15;
            float bs = 0.f;
            if (EPI==EPI_BIAS_RES || EPI==EPI_BIAS_RELU || EPI==EPI_BIAS || EPI==EPI_HSPLIT)
                bs = bias[n];
#pragma unroll
            for (int r = 0; r < 4; r++){
                const int m = m0 + wm + i * 16 + quad * 4 + r;
                float v = acc[i][j][r] + bs;
                if (EPI==EPI_BIAS_RES)
                    v += ((const float*)ext)[(size_t)m * ldext + n];
                if (EPI==EPI_BIAS_RELU || EPI==EPI_HSPLIT)
                    v = fmaxf(v, 0.f);
                if (EPI==EPI_RELUSQ){ float t = fmaxf(v * scale, 0.f); v = t * t * SCALE_A; }
                if (EPI==EPI_GATE)
                    v *= bf2f(((const u16*)ext)[(size_t)z * sEb + (size_t)m * ldext + n]);
                if (EPI==EPI_HSPLIT){
                    if (n < hsplit){
                        if (OT==OT_FP8) C8[(size_t)m * ldc + n] = f2fp8(v * SCALE_V);
                        else            Ch[(size_t)m * ldc + n] = f2bf(v);
                    } else {
                        out2[(size_t)m * ldc + n - hsplit] = f2bf(v);
                    }
                } else if (OT==OT_FP8){
                    C8[zc + (size_t)m * ldc + n] = f2fp8(v);
                } else if (OT==OT_BF16){
                    Ch[zc + (size_t)m * ldc + n] = f2bf(v);
                } else {
                    Cf[zc + (size_t)m * ldc + n] = v;
                }
            }
        }
    }
}

// ---------------- fp8 MFMA GEMM (Vg = (A @ vT) * 2^-15 * gate) ----------------
__global__ __launch_bounds__(256)
void mgemm8(const u8* __restrict__ A, const u8* __restrict__ B, u16* __restrict__ C,
            int K, int lda, int ldb, int ldc,
            long sAb, long sBb, long sCb,
            const u16* __restrict__ gate, int ldext, long sEb)
{
    __shared__ u8 sA[4096];    // [kc 0..1][row 0..127][16B]
    __shared__ u8 sB[4096];
    const int tid = threadIdx.x;
    const int m0 = blockIdx.y * 128, n0 = blockIdx.x * 128;
    const int z  = blockIdx.z;
    const u8* Az = A + (size_t)z * sAb;
    const u8* Bz = B + (size_t)z * sBb;

    const int lane = tid & 63, quad = lane >> 4, l15 = lane & 15;
    const int wave = tid >> 6;
    const int wm = (wave >> 1) * 64, wn = (wave & 1) * 64;

    const u8* gA = Az + (size_t)(m0 + (tid & 127)) * lda + (tid >> 7) * 16;
    const u8* gB = Bz + (size_t)(n0 + (tid & 127)) * ldb + (tid >> 7) * 16;
    const int lo = (tid & 192) * 16;

    f32x4 acc[4][4];
#pragma unroll
    for (int i = 0; i < 4; i++)
#pragma unroll
        for (int j = 0; j < 4; j++) acc[i][j] = (f32x4){0.f,0.f,0.f,0.f};

    const u8* fA = sA + (quad >> 1) * 2048 + (size_t)(wm + l15) * 16 + (quad & 1) * 8;
    const u8* fB = sB + (quad >> 1) * 2048 + (size_t)(wn + l15) * 16 + (quad & 1) * 8;

    for (int k0 = 0; k0 < K; k0 += 32){
        gl2lds16(gA + k0, (char*)sA + lo);
        gl2lds16(gB + k0, (char*)sB + lo);
        __syncthreads();
        long a[4], b[4];
#pragma unroll
        for (int t = 0; t < 4; t++){
            a[t] = *(const long*)(fA + t * 256);
            b[t] = *(const long*)(fB + t * 256);
        }
#pragma unroll
        for (int i = 0; i < 4; i++)
#pragma unroll
            for (int j = 0; j < 4; j++)
                acc[i][j] = __builtin_amdgcn_mfma_f32_16x16x32_fp8_fp8(a[i], b[j], acc[i][j], 0, 0, 0);
        __syncthreads();
    }

    const size_t zc = (size_t)z * sCb;
#pragma unroll
    for (int i = 0; i < 4; i++){
#pragma unroll
        for (int j = 0; j < 4; j++){
            const int n = n0 + wn + j * 16 + l15;
#pragma unroll
            for (int r = 0; r < 4; r++){
                const int m = m0 + wm + i * 16 + quad * 4 + r;
                float v = acc[i][j][r] * INV_SCALE_AV
                        * bf2f(gate[(size_t)z * sEb + (size_t)m * ldext + n]);
                C[zc + (size_t)m * ldc + n] = f2bf(v);
            }
        }
    }
}

// ---------------- Row LayerNorm over D=512 ----------------
template<bool OUT_BF, bool ADD_RES, bool SUM2>
__global__ __launch_bounds__(256)
void ln_k(const float* __restrict__ in, const float* __restrict__ g,
          const float* __restrict__ b, const float* __restrict__ res,
          const float* __restrict__ in2, const float* __restrict__ bias2,
          void* __restrict__ out)
{
    const int row = blockIdx.x, tid = threadIdx.x;
    float2 v = *(const float2*)(in + (size_t)row * 512 + tid * 2);
    if (SUM2){
        const float2 w = *(const float2*)(in2 + (size_t)row * 512 + tid * 2);
        const float2 bb2 = *(const float2*)(bias2 + tid * 2);
        v.x += w.x + bb2.x; v.y += w.y + bb2.y;
    }
    float s = v.x + v.y, ss = v.x * v.x + v.y * v.y;
#pragma unroll
    for (int off = 32; off > 0; off >>= 1){
        s  += __shfl_down(s,  off);
        ss += __shfl_down(ss, off);
    }
    __shared__ float sbuf[8], ssbuf[8];
    const int wid = tid >> 6, lane = tid & 63;
    if (lane == 0){ sbuf[wid] = s; ssbuf[wid] = ss; }
    __syncthreads();
    if (tid == 0){
        float S = 0.f, SS = 0.f;
#pragma unroll
        for (int i = 0; i < 4; i++){ S += sbuf[i]; SS += ssbuf[i]; }
        const float mean = S * (1.f/512.f);
        const float var  = SS * (1.f/512.f) - mean * mean;
        sbuf[4]  = mean;
        ssbuf[4] = rsqrtf(var + LN_EPS);
    }
    __syncthreads();
    const float mean = sbuf[4], rstd = ssbuf[4];
    const float2 gg = *(const float2*)(g + tid * 2);
    const float2 bb = *(const float2*)(b + tid * 2);
    float ox = (v.x - mean) * rstd * gg.x + bb.x;
    float oy = (v.y - mean) * rstd * gg.y + bb.y;
    if (ADD_RES){
        const float2 r = *(const float2*)(res + (size_t)row * 512 + tid * 2);
        ox += r.x; oy += r.y;
    }
    if (OUT_BF){
        unsigned pk = ((unsigned)f2bf(oy) << 16) | (unsigned)f2bf(ox);
        ((unsigned*)out)[(size_t)row * 256 + tid] = pk;
    } else {
        *(float2*)((float*)out + (size_t)row * 512 + tid * 2) = make_float2(ox, oy);
    }
}

// ---------------- fused f32 -> bf16 casts ----------------
__global__ __launch_bounds__(256)
void castall_k(const float* __restrict__ x, const float* __restrict__ Wm,
               const float* __restrict__ Wh, const float* __restrict__ Wq,
               const float* __restrict__ Wo,
               u16* __restrict__ xb, u16* __restrict__ Wmb, u16* __restrict__ Whb,
               u16* __restrict__ Wqb, u16* __restrict__ Wob)
{
    const int i = blockIdx.x * 256 + threadIdx.x;
    const float* src; u16* dst; int off;
    if      (i < 1048576){ src = x;  dst = xb;  off = i; }
    else if (i < 1114112){ src = Wm; dst = Wmb; off = i - 1048576; }
    else if (i < 1507328){ src = Wh; dst = Whb; off = i - 1114112; }
    else if (i < 1540096){ src = Wq; dst = Wqb; off = i - 1507328; }
    else if (i < 1736704){ src = Wo; dst = Wob; off = i - 1540096; }
    else return;
    const float4 v = ((const float4*)src)[off];
    ushort4 o; o.x = f2bf(v.x); o.y = f2bf(v.y); o.z = f2bf(v.z); o.w = f2bf(v.w);
    ((ushort4*)dst)[off] = o;
}

__global__ __launch_bounds__(256)
void wbt_k(const float* __restrict__ Wb, u16* __restrict__ WbT){
    int i = blockIdx.x * 256 + threadIdx.x;
    int e = i >> 8, d = i & 255;
    WbT[e * 256 + d] = f2bf(Wb[d * 256 + e]);
}

// vT[b][h][s] = v[b][s][h], fp8, 64x64 tiles
__global__ __launch_bounds__(256)
void tr8_k(const u8* __restrict__ v, u8* __restrict__ vT, int S, int HID){
    const int b = blockIdx.z;
    const int h0 = blockIdx.x * 64, s0 = blockIdx.y * 64;
    __shared__ u8 t[64][68];
    const u8* vb = v + (size_t)b * S * HID;
    u8* vTb = vT + (size_t)b * HID * S;
    const int tid = threadIdx.x;
#pragma unroll
    for (int i = 0; i < 4; i++){
        int idx = tid + i * 256;
        int r = idx >> 4, c4 = (idx & 15) * 4;
        uchar4 u = *(const uchar4*)(vb + (size_t)(s0 + r) * HID + h0 + c4);
        t[r][c4] = u.x; t[r][c4+1] = u.y; t[r][c4+2] = u.z; t[r][c4+3] = u.w;
    }
    __syncthreads();
#pragma unroll
    for (int i = 0; i < 4; i++){
        int idx = tid + i * 256;
        int r = idx >> 4, c4 = (idx & 15) * 4;
        uchar4 u;
        u.x = t[c4][r]; u.y = t[c4+1][r]; u.z = t[c4+2][r]; u.w = t[c4+3][r];
        *(uchar4*)(vTb + (size_t)(h0 + r) * S + s0 + c4) = u;
    }
}

extern "C" void kernel_launch(void* const* d_in, const int* in_sizes, int n_in,
                              void* d_out, int out_size, void* d_ws, size_t ws_size,
                              hipStream_t stream)
{
    const float* x  = (const float*)d_in[0];
    const float* Wm = (const float*)d_in[1];
    const float* bm = (const float*)d_in[2];
    const float* g1 = (const float*)d_in[3];
    const float* b1 = (const float*)d_in[4];
    const float* Wh = (const float*)d_in[5];
    const float* bh = (const float*)d_in[6];
    const float* Wq = (const float*)d_in[7];
    const float* bq = (const float*)d_in[8];
    const float* Wb = (const float*)d_in[9];
    const float* Wo = (const float*)d_in[10];
    const float* bo = (const float*)d_in[11];
    const float* g2 = (const float*)d_in[12];
    const float* b2 = (const float*)d_in[13];
    float* out = (float*)d_out;
    (void)in_sizes; (void)n_in; (void)out_size; (void)ws_size;

    const int Bn=4, S=2048, D=512, QKD=256, HID=1536, H2=3072;
    const int M = Bn * S; // 8192

    char* p = (char*)d_ws;
    auto alloc = [&](size_t bytes)->void*{ void* r = p; p += (bytes + 255) & ~(size_t)255; return r; };
    u16*  xbf  = (u16*) alloc((size_t)M*D*2);     // later reused as normed_bf
    u16*  Wmbf = (u16*) alloc((size_t)D*D*2);
    u16*  Whbf = (u16*) alloc((size_t)H2*D*2);
    u16*  Wqbf = (u16*) alloc((size_t)QKD*D*2);
    u16*  Wobf = (u16*) alloc((size_t)D*HID*2);
    u16*  WbT  = (u16*) alloc((size_t)QKD*QKD*2);
    float* ybuf= (float*)alloc((size_t)M*D*4);
    float* ybuf2=(float*)alloc((size_t)M*D*4);
    u16*  Zb   = (u16*) alloc((size_t)M*QKD*2);
    u16*  ZWbb = (u16*) alloc((size_t)M*QKD*2);
    u8*   v8   = (u8*)  alloc((size_t)M*HID);
    u16*  gbf  = (u16*) alloc((size_t)M*HID*2);
    u8*   vT8  = (u8*)  alloc((size_t)M*HID);
    u8*   A8   = (u8*)  alloc((size_t)M*S);
    u16*  Vgbf = (u16*) alloc((size_t)M*HID*2);
    u16*  nrm  = xbf;

    dim3 blk(256);

    castall_k<<<dim3(6784), blk, 0, stream>>>(x, Wm, Wh, Wq, Wo, xbf, Wmbf, Whbf, Wqbf, Wobf);
    wbt_k<<<dim3(QKD*QKD/256), blk, 0, stream>>>(Wb, WbT);

    // 1. y = x@Wm^T + bm + x   (fp32 out)
    mgemm<EPI_BIAS_RES,OT_F32><<<dim3(D/128, M/128, 1), blk, 0, stream>>>(
        xbf, Wmbf, ybuf, D, D, D, D, 0,0,0, bm, x, D, 0, 1.f, nullptr, 0);
    // 2. normed = LN(y) -> bf16
    ln_k<true,false,false><<<dim3(M), blk, 0, stream>>>(ybuf, g1, b1, nullptr, nullptr, nullptr, nrm);
    // 3. h = relu(normed@Wh^T + bh) -> v fp8 (x8) | gate bf16
    mgemm<EPI_HSPLIT,OT_FP8><<<dim3(H2/128, M/128, 1), blk, 0, stream>>>(
        nrm, Whbf, v8, D, D, D, HID, 0,0,0, bh, nullptr, 0, 0, 1.f, gbf, HID);
    // 4. Z = relu(normed@Wq^T + bq) -> bf16
    mgemm<EPI_BIAS_RELU,OT_BF16><<<dim3(QKD/128, M/128, 1), blk, 0, stream>>>(
        nrm, Wqbf, Zb, D, D, D, QKD, 0,0,0, bq, nullptr, 0, 0, 1.f, nullptr, 0);
    // 5. ZWb = Z @ Wb -> bf16
    mgemm<EPI_NONE,OT_BF16><<<dim3(QKD/128, M/128, 1), blk, 0, stream>>>(
        Zb, WbT, ZWbb, QKD, QKD, QKD, QKD, 0,0,0, nullptr, nullptr, 0, 0, 1.f, nullptr, 0);
    // 6a. A = relu(ZWb_b @ Z_b^T / S)^2 * 2^12 -> fp8, batched over z
    mgemm<EPI_RELUSQ,OT_FP8><<<dim3(S/128, S/128, Bn), blk, 0, stream>>>(
        ZWbb, Zb, A8, QKD, QKD, QKD, S,
        (long)S*QKD, (long)S*QKD, (long)S*S,
        nullptr, nullptr, 0, 0, 1.f/(float)S, nullptr, 0);
    // 6b. vT = transpose(v) per batch (fp8)
    tr8_k<<<dim3(HID/64, S/64, Bn), blk, 0, stream>>>(v8, vT8, S, HID);
    // 6c. Vg = (A @ v) * 2^-15 * gate -> bf16, batched, fp8 MFMA
    mgemm8<<<dim3(HID/128, S/128, Bn), blk, 0, stream>>>(
        A8, vT8, Vgbf, S, S, S, HID,
        (long)S*S, (long)HID*S, (long)S*HID,
        gbf, HID, (long)S*HID);
    // 7. t halves = Vg@Wo^T  (split-K, fp32 out; bias added in LN2)
    mgemm<EPI_NONE,OT_F32><<<dim3(D/128, M/128, 2), blk, 0, stream>>>(
        Vgbf, Wobf, ybuf, HID/2, HID, HID, D,
        (long)HID/2, (long)HID/2, (long)M*D,
        nullptr, nullptr, 0, 0, 1.f, nullptr, 0);
    // 8. out = LN(t0 + t1 + bo) + x
    ln_k<false,true,true><<<dim3(M), blk, 0, stream>>>(ybuf, g2, b2, x, ybuf2, bo, out);
}